// Round 6
// baseline (1102.264 us; speedup 1.0000x reference)
//
#include <hip/hip_runtime.h>
#include <hip/hip_bf16.h>
#include <math.h>

typedef long long ll;
typedef unsigned short ushort_t;
typedef __attribute__((ext_vector_type(8))) __bf16 bf16x8;
typedef __attribute__((ext_vector_type(4))) float f32x4;

// ---------------- helpers ----------------
__device__ __forceinline__ ushort_t f2bf(float f) {
    __hip_bfloat16 h = __float2bfloat16(f);
    return *reinterpret_cast<ushort_t*>(&h);
}
__device__ __forceinline__ float bf2f(ushort_t u) {
    return __uint_as_float(((unsigned)u) << 16);
}
// global->LDS DMA: lds dest wave-uniform; lane i deposits at dest + i*16
__device__ __forceinline__ void stage16(const void* g_lane, void* lds_uniform) {
    __builtin_amdgcn_global_load_lds(
        (const __attribute__((address_space(1))) unsigned int*)g_lane,
        (__attribute__((address_space(3))) unsigned int*)lds_uniform, 16, 0, 0);
}

// ---------------- bf16 MFMA GEMM (B^T form), TK=64, double-buffered ----------------
//   C[z][m,n] = sum_k A[z][m,k] * B[z][n,k];  z1 = z/Z2, z2 = z%Z2
#define TM 128
#define TN 128
#define TK 64

__global__ __launch_bounds__(256)
void gemm_bf16(const ushort_t* __restrict__ Ab, const ushort_t* __restrict__ Bb,
               void* __restrict__ Cb,
               int M, int N, int K,
               int a_rs, int b_rs, int c_rs, int Z2,
               ll a_bs1, ll a_bs2, ll b_bs1, ll b_bs2, ll c_bs1, ll c_bs2,
               int out_f32)
{
    const int m0 = blockIdx.y * TM;
    const int n0 = blockIdx.x * TN;
    const int z1 = blockIdx.z / Z2, z2 = blockIdx.z % Z2;

    const ushort_t* A = Ab + z1 * a_bs1 + z2 * a_bs2;
    const ushort_t* B = Bb + z1 * b_bs1 + z2 * b_bs2;

    __shared__ ushort_t As[2][TM][TK];
    __shared__ ushort_t Bs[2][TN][TK];

    const int tid  = threadIdx.x;
    const int w    = tid >> 6;
    const int l    = tid & 63;
    const int lo16 = l & 15;
    const int quad = l >> 4;
    const int wm0  = (w & 1) * 64;
    const int wn0  = (w >> 1) * 64;

    const int srow  = l >> 3;
    const int sunit = (l & 7) ^ srow;

    f32x4 acc[4][4];
    const f32x4 zero = {0.f, 0.f, 0.f, 0.f};
#pragma unroll
    for (int mi = 0; mi < 4; ++mi)
#pragma unroll
        for (int nj = 0; nj < 4; ++nj) acc[mi][nj] = zero;

    const int nIter = K / TK;

#pragma unroll
    for (int i = 0; i < 4; ++i) {
        const int rr = w * 32 + i * 8;
        stage16(A + (ll)(m0 + rr + srow) * a_rs + sunit * 8, &As[0][rr][0]);
        stage16(B + (ll)(n0 + rr + srow) * b_rs + sunit * 8, &Bs[0][rr][0]);
    }

    int buf = 0;
    for (int it = 0; it < nIter; ++it) {
        __syncthreads();
        if (it + 1 < nIter) {
            const int k0 = (it + 1) * TK;
            const int nb = buf ^ 1;
#pragma unroll
            for (int i = 0; i < 4; ++i) {
                const int rr = w * 32 + i * 8;
                stage16(A + (ll)(m0 + rr + srow) * a_rs + (k0 + sunit * 8), &As[nb][rr][0]);
                stage16(B + (ll)(n0 + rr + srow) * b_rs + (k0 + sunit * 8), &Bs[nb][rr][0]);
            }
        }
#pragma unroll
        for (int h = 0; h < 2; ++h) {
            const int phys = (h * 4 + quad) ^ (lo16 & 7);
            bf16x8 af[4], bfr[4];
#pragma unroll
            for (int mi = 0; mi < 4; ++mi)
                af[mi] = *(const bf16x8*)&As[buf][wm0 + mi * 16 + lo16][phys * 8];
#pragma unroll
            for (int nj = 0; nj < 4; ++nj)
                bfr[nj] = *(const bf16x8*)&Bs[buf][wn0 + nj * 16 + lo16][phys * 8];
#pragma unroll
            for (int mi = 0; mi < 4; ++mi)
#pragma unroll
                for (int nj = 0; nj < 4; ++nj)
                    acc[mi][nj] = __builtin_amdgcn_mfma_f32_16x16x32_bf16(
                        af[mi], bfr[nj], acc[mi][nj], 0, 0, 0);
        }
        buf ^= 1;
    }

    if (out_f32) {
        float* C = (float*)Cb + z1 * c_bs1 + z2 * c_bs2;
#pragma unroll
        for (int mi = 0; mi < 4; ++mi)
#pragma unroll
            for (int r = 0; r < 4; ++r) {
                const ll row = m0 + wm0 + mi * 16 + quad * 4 + r;
                float* cr = C + row * (ll)c_rs + (n0 + wn0 + lo16);
#pragma unroll
                for (int nj = 0; nj < 4; ++nj) cr[nj * 16] = acc[mi][nj][r];
            }
    } else {
        ushort_t* C = (ushort_t*)Cb + z1 * c_bs1 + z2 * c_bs2;
#pragma unroll
        for (int mi = 0; mi < 4; ++mi)
#pragma unroll
            for (int r = 0; r < 4; ++r) {
                const ll row = m0 + wm0 + mi * 16 + quad * 4 + r;
                ushort_t* cr = C + row * (ll)c_rs + (n0 + wn0 + lo16);
#pragma unroll
                for (int nj = 0; nj < 4; ++nj) cr[nj * 16] = f2bf(acc[mi][nj][r]);
            }
    }
}

// ---------------- fused flash-MLA attention, 2-wave blocks ----------------
// Grid (32,16,2), 128 thr. Wave w owns q-rows [32w,32w+32) of a 64-row tile
// (2 m-tiles, Q A-frags in regs) -> each LDS K/V fragment read feeds 2 MFMAs.
// LDS 48KB -> 3 blocks/CU co-resident to hide single-buffered staging.
#define QUP_RS 3072
#define XP_RS  1152

__global__ __launch_bounds__(128, 2)
void flash_mla(const ushort_t* __restrict__ QP,    // [2][2048][3072]: q_up | q_r
               const ushort_t* __restrict__ WukT,  // [16][512][128]
               const ushort_t* __restrict__ XP,    // [2][2048][1152]: cq | K(576) | pad
               const ushort_t* __restrict__ VT,    // [2][16][128][2048]
               float* __restrict__ out,            // [2][2048][2048]
               float scale)
{
    const int qt = 31 - blockIdx.x;
    const int h  = blockIdx.y;
    const int b  = blockIdx.z;
    const int t0 = qt * 64;

    // layout: build: Aq[64][128]@0 | Bw[64][128]@16384 | Cstage[2][32][64]@32768
    //         main : Ks[32][72u]@0 (36864) | Vs[128][4u]@36864 (8192) | P[2][32][32]@45056
    __shared__ __align__(16) char smem[49152];

    const int tid  = threadIdx.x;
    const int w    = tid >> 6;
    const int l    = tid & 63;
    const int lo16 = l & 15;
    const int quad = l >> 4;

    // ---------- phase 1: build Q A-frags (k-tiles of 32 over 576) ----------
    bf16x8 qa[2][18];
    {
#pragma unroll
        for (int i = 0; i < 8; ++i) {
            int p = w * 512 + i * 64 + l;
            int r = p >> 4, u = p & 15;
            int ul = u ^ (r & 15);
            stage16(QP + (ll)(b * 2048 + t0 + r) * QUP_RS + h * 128 + ul * 8,
                    smem + (ll)(w * 512 + i * 64) * 16);
            stage16(WukT + ((ll)h * 512 + r) * 128 + ul * 8,
                    smem + 16384 + (ll)(w * 512 + i * 64) * 16);
        }
        __syncthreads();

        bf16x8 ab[2][4];
#pragma unroll
        for (int kd = 0; kd < 4; ++kd) {
            int phys = (kd * 4 + quad) ^ lo16;
#pragma unroll
            for (int mi = 0; mi < 2; ++mi) {
                int row = w * 32 + mi * 16 + lo16;
                ab[mi][kd] = *(const bf16x8*)(smem + row * 256 + phys * 16);
            }
        }

        char* Cw = smem + 32768 + w * 4096;
        for (int c = 0; c < 8; ++c) {
            f32x4 qc[2][4];
#pragma unroll
            for (int mi = 0; mi < 2; ++mi)
#pragma unroll
                for (int nt = 0; nt < 4; ++nt) qc[mi][nt] = (f32x4){0.f, 0.f, 0.f, 0.f};
#pragma unroll
            for (int nt = 0; nt < 4; ++nt)
#pragma unroll
                for (int kd = 0; kd < 4; ++kd) {
                    int phys = (kd * 4 + quad) ^ lo16;
                    bf16x8 bb = *(const bf16x8*)(smem + 16384 + (nt * 16 + lo16) * 256 + phys * 16);
                    qc[0][nt] = __builtin_amdgcn_mfma_f32_16x16x32_bf16(ab[0][kd], bb, qc[0][nt], 0, 0, 0);
                    qc[1][nt] = __builtin_amdgcn_mfma_f32_16x16x32_bf16(ab[1][kd], bb, qc[1][nt], 0, 0, 0);
                }
#pragma unroll
            for (int mi = 0; mi < 2; ++mi)
#pragma unroll
                for (int nt = 0; nt < 4; ++nt)
#pragma unroll
                    for (int r = 0; r < 4; ++r) {
                        int row = mi * 16 + quad * 4 + r;
                        int col = nt * 16 + lo16;
                        *(ushort_t*)(Cw + row * 128 + (((col >> 3) ^ (row & 7)) << 4) + (col & 7) * 2)
                            = f2bf(qc[mi][nt][r]);
                    }
#pragma unroll
            for (int mi = 0; mi < 2; ++mi)
#pragma unroll
                for (int kk = 0; kk < 2; ++kk) {
                    int row = mi * 16 + lo16;
                    int phys = (kk * 4 + quad) ^ (lo16 & 7);
                    qa[mi][2 * c + kk] = *(const bf16x8*)(Cw + row * 128 + phys * 16);
                }
            if (c < 7) {
                __syncthreads();
#pragma unroll
                for (int i = 0; i < 8; ++i) {
                    int p = w * 512 + i * 64 + l;
                    int r = p >> 4, u = p & 15;
                    int ul = u ^ (r & 15);
                    stage16(WukT + ((ll)h * 512 + (c + 1) * 64 + r) * 128 + ul * 8,
                            smem + 16384 + (ll)(w * 512 + i * 64) * 16);
                }
                __syncthreads();
            }
        }
        // rope tail (k-tiles 16,17) from QP cols 2048..3071
#pragma unroll
        for (int mi = 0; mi < 2; ++mi)
#pragma unroll
            for (int j = 0; j < 2; ++j)
                qa[mi][16 + j] = *(const bf16x8*)(QP +
                    (ll)(b * 2048 + t0 + w * 32 + mi * 16 + lo16) * QUP_RS +
                    2048 + h * 64 + j * 32 + quad * 8);
    }

    // ---------- phase 2: K/V loop ----------
    f32x4 oacc[2][8];
    const f32x4 zero = {0.f, 0.f, 0.f, 0.f};
#pragma unroll
    for (int mi = 0; mi < 2; ++mi)
#pragma unroll
        for (int dt = 0; dt < 8; ++dt) oacc[mi][dt] = zero;
    float mrow[2][4], lrow[2][4];
#pragma unroll
    for (int mi = 0; mi < 2; ++mi)
#pragma unroll
        for (int r = 0; r < 4; ++r) { mrow[mi][r] = -3.0e38f; lrow[mi][r] = 0.f; }

    char* Pw = smem + 45056 + w * 2048;
    const int nst = 2 * qt + 2;

    for (int st = 0; st < nst; ++st) {
        const int s0 = st * 32;
        __syncthreads();
        // stage Ks: wave w rows [16w,16w+16), 72 units/row, low-3 XOR swizzle
#pragma unroll
        for (int i = 0; i < 18; ++i) {
            int p = i * 64 + l;                     // 0..1151
            int r = 16 * w + p / 72;
            int u = p % 72;
            int ul = (u & ~7) | ((u & 7) ^ (r & 7));
            stage16(XP + (ll)(b * 2048 + s0 + r) * XP_RS + 512 + ul * 8,
                    smem + (ll)(w * 1152 + i * 64) * 16);
        }
        // stage Vs[128][4 units]
#pragma unroll
        for (int i = 0; i < 4; ++i) {
            int p = 256 * w + i * 64 + l;
            int r = p >> 2, u = p & 3;
            int ul = u ^ (r & 3);
            stage16(VT + ((ll)(b * 16 + h) * 128 + r) * 2048 + s0 + ul * 8,
                    smem + 36864 + (ll)p * 16 - (ll)l * 16 + (ll)l * 16);
        }
        __syncthreads();

        // S = Q.K^T : per wave 32x32, each kb read feeds 2 MFMAs
        f32x4 sc[2][2];
        sc[0][0] = zero; sc[0][1] = zero; sc[1][0] = zero; sc[1][1] = zero;
#pragma unroll
        for (int kt = 0; kt < 18; ++kt)
#pragma unroll
            for (int nt = 0; nt < 2; ++nt) {
                int u = kt * 4 + quad;
                int phys = (u & ~7) | ((u & 7) ^ (lo16 & 7));
                bf16x8 kb = *(const bf16x8*)(smem + (nt * 16 + lo16) * 1152 + phys * 16);
                sc[0][nt] = __builtin_amdgcn_mfma_f32_16x16x32_bf16(qa[0][kt], kb, sc[0][nt], 0, 0, 0);
                sc[1][nt] = __builtin_amdgcn_mfma_f32_16x16x32_bf16(qa[1][kt], kb, sc[1][nt], 0, 0, 0);
            }

        // scale + causal mask (relative coords; s > t masked)
        const int srel = s0 - t0;
#pragma unroll
        for (int mi = 0; mi < 2; ++mi)
#pragma unroll
            for (int nt = 0; nt < 2; ++nt)
#pragma unroll
                for (int r = 0; r < 4; ++r) sc[mi][nt][r] *= scale;
        if (st >= 2 * qt + w) {
#pragma unroll
            for (int mi = 0; mi < 2; ++mi)
#pragma unroll
                for (int nt = 0; nt < 2; ++nt)
#pragma unroll
                    for (int r = 0; r < 4; ++r)
                        if ((srel + nt * 16 + lo16) > (32 * w + mi * 16 + quad * 4 + r))
                            sc[mi][nt][r] = -INFINITY;
        }

        // online softmax (rows span 16 lanes of each quad group)
#pragma unroll
        for (int mi = 0; mi < 2; ++mi)
#pragma unroll
            for (int r = 0; r < 4; ++r) {
                float tm = fmaxf(sc[mi][0][r], sc[mi][1][r]);
#pragma unroll
                for (int off = 1; off <= 8; off <<= 1)
                    tm = fmaxf(tm, __shfl_xor(tm, off, 64));
                float mnew = fmaxf(mrow[mi][r], tm);
                float al = __expf(mrow[mi][r] - mnew);
                mrow[mi][r] = mnew;
                sc[mi][0][r] = __expf(sc[mi][0][r] - mnew);
                sc[mi][1][r] = __expf(sc[mi][1][r] - mnew);
                float rs = sc[mi][0][r] + sc[mi][1][r];
#pragma unroll
                for (int off = 1; off <= 8; off <<= 1)
                    rs += __shfl_xor(rs, off, 64);
                lrow[mi][r] = lrow[mi][r] * al + rs;
#pragma unroll
                for (int dt = 0; dt < 8; ++dt) oacc[mi][dt][r] *= al;
            }

        // P -> bf16 -> wave-private LDS -> A-frags
#pragma unroll
        for (int mi = 0; mi < 2; ++mi)
#pragma unroll
            for (int nt = 0; nt < 2; ++nt)
#pragma unroll
                for (int r = 0; r < 4; ++r) {
                    int row = mi * 16 + quad * 4 + r;
                    int col = nt * 16 + lo16;
                    *(ushort_t*)(Pw + row * 64 + (((col >> 3) ^ (row & 3)) << 4) + (col & 7) * 2)
                        = f2bf(sc[mi][nt][r]);
                }
        bf16x8 pf[2];
#pragma unroll
        for (int mi = 0; mi < 2; ++mi) {
            int row = mi * 16 + lo16;
            int phys = quad ^ (lo16 & 3);
            pf[mi] = *(const bf16x8*)(Pw + row * 64 + phys * 16);
        }

        // O += P.V : each vb read feeds 2 MFMAs
#pragma unroll
        for (int dt = 0; dt < 8; ++dt) {
            int r2 = dt * 16 + lo16;
            int phys = quad ^ (lo16 & 3);
            bf16x8 vb = *(const bf16x8*)(smem + 36864 + r2 * 64 + phys * 16);
            oacc[0][dt] = __builtin_amdgcn_mfma_f32_16x16x32_bf16(pf[0], vb, oacc[0][dt], 0, 0, 0);
            oacc[1][dt] = __builtin_amdgcn_mfma_f32_16x16x32_bf16(pf[1], vb, oacc[1][dt], 0, 0, 0);
        }
    }

    // ---------- epilogue ----------
#pragma unroll
    for (int mi = 0; mi < 2; ++mi)
#pragma unroll
        for (int r = 0; r < 4; ++r) {
            const float inv = 1.0f / lrow[mi][r];
            const ll row = (ll)(b * 2048 + t0 + 32 * w + mi * 16 + quad * 4 + r);
#pragma unroll
            for (int dt = 0; dt < 8; ++dt)
                out[row * 2048 + h * 128 + dt * 16 + lo16] = oacc[mi][dt][r] * inv;
        }
}

// ---------------- conversion / layout kernels ----------------
__global__ void cvt_f32_bf16(const float* __restrict__ in, ushort_t* __restrict__ out, ll n4)
{
    ll i = (ll)blockIdx.x * 256 + threadIdx.x;
    if (i >= n4) return;
    float4 v = *(const float4*)(in + i * 4);
    ushort4 u;
    u.x = f2bf(v.x); u.y = f2bf(v.y); u.z = f2bf(v.z); u.w = f2bf(v.w);
    *(ushort4*)(out + i * 4) = u;
}

// WB1 [1152][2048]: 0..511 W_dq | 512..1023 W_dkv | 1024..1087 W_kr | pad 0
__global__ void build_wb1(const float* __restrict__ Wdq, const float* __restrict__ Wdkv,
                          const float* __restrict__ Wkr, ushort_t* __restrict__ out)
{
    ll i4 = ((ll)blockIdx.x * 256 + threadIdx.x) * 4;
    if (i4 >= (ll)1152 * 2048) return;
    int row = (int)(i4 >> 11);
    int col = (int)(i4 & 2047);
    float4 v = make_float4(0.f, 0.f, 0.f, 0.f);
    if (row < 512)       v = *(const float4*)(Wdq + (ll)row * 2048 + col);
    else if (row < 1024) v = *(const float4*)(Wdkv + (ll)(row - 512) * 2048 + col);
    else if (row < 1088) v = *(const float4*)(Wkr + (ll)(row - 1024) * 2048 + col);
    ushort4 u;
    u.x = f2bf(v.x); u.y = f2bf(v.y); u.z = f2bf(v.z); u.w = f2bf(v.w);
    *(ushort4*)(out + i4) = u;
}

__global__ void transpose_f32_bf16(const float* __restrict__ in, ushort_t* __restrict__ out,
                                   int R, int C, ll in_bs, ll out_bs)
{
    __shared__ float tile[32][33];
    const float* I = in + (ll)blockIdx.z * in_bs;
    ushort_t*    O = out + (ll)blockIdx.z * out_bs;
    int r0 = blockIdx.y * 32, c0 = blockIdx.x * 32;
    int tx = threadIdx.x & 31, ty = threadIdx.x >> 5;
#pragma unroll
    for (int i = 0; i < 4; ++i)
        tile[ty + i * 8][tx] = I[(ll)(r0 + ty + i * 8) * C + (c0 + tx)];
    __syncthreads();
#pragma unroll
    for (int i = 0; i < 4; ++i)
        O[(ll)(c0 + ty + i * 8) * R + (r0 + tx)] = f2bf(tile[tx][ty + i * 8]);
}

// rope on XP cols [1024..1088) in place (bf16)
__global__ void rope_kr(ushort_t* __restrict__ XP, const float* __restrict__ cb,
                        const float* __restrict__ sb)
{
    int idx = blockIdx.x * 256 + threadIdx.x;   // 2*2048*32
    if (idx >= 2 * 2048 * 32) return;
    int j = idx & 31, t = (idx >> 5) & 2047, b = idx >> 16;
    float c = cb[t * 32 + j], s = sb[t * 32 + j];
    ushort_t* p = XP + ((ll)(b * 2048 + t)) * 1152 + 1024 + 2 * j;
    float re = bf2f(p[0]), im = bf2f(p[1]);
    p[0] = f2bf(re * c - im * s);
    p[1] = f2bf(re * s + im * c);
}

// rope on QP cols [2048..3072) in place (bf16)
__global__ void rope_qr_ip(ushort_t* __restrict__ QP, const float* __restrict__ cb,
                           const float* __restrict__ sb)
{
    int idx = blockIdx.x * 256 + threadIdx.x;   // 4096*512 pairs
    if (idx >= 4096 * 512) return;
    int pj = idx & 511, h = pj >> 5, j = pj & 31;
    int row = idx >> 9;
    int t = row & 2047;
    float c = cb[t * 32 + j], s = sb[t * 32 + j];
    ll base = (ll)row * 3072 + 2048 + h * 64 + 2 * j;
    float re = bf2f(QP[base]), im = bf2f(QP[base + 1]);
    QP[base]     = f2bf(re * c - im * s);
    QP[base + 1] = f2bf(re * s + im * c);
}

// ---------------- host ----------------
static inline void gemmb(hipStream_t st, const ushort_t* A, const ushort_t* B, void* C,
                         int M, int N, int K, int a_rs, int b_rs, int c_rs,
                         int nb, int Z2,
                         ll a_bs1, ll a_bs2, ll b_bs1, ll b_bs2, ll c_bs1, ll c_bs2,
                         int of32)
{
    dim3 g(N / TN, M / TM, nb);
    gemm_bf16<<<g, 256, 0, st>>>(A, B, C, M, N, K, a_rs, b_rs, c_rs, Z2,
                                 a_bs1, a_bs2, b_bs1, b_bs2, c_bs1, c_bs2, of32);
}

extern "C" void kernel_launch(void* const* d_in, const int* in_sizes, int n_in,
                              void* d_out, int out_size, void* d_ws, size_t ws_size,
                              hipStream_t stream)
{
    const float* x     = (const float*)d_in[0];
    const float* cosb  = (const float*)d_in[1];
    const float* sinb  = (const float*)d_in[2];
    const float* W_dq  = (const float*)d_in[3];
    const float* W_uq  = (const float*)d_in[4];
    const float* W_dkv = (const float*)d_in[5];
    const float* W_uk  = (const float*)d_in[6];
    const float* W_uv  = (const float*)d_in[7];
    const float* W_qr  = (const float*)d_in[8];
    const float* W_kr  = (const float*)d_in[9];
    const float* W_o   = (const float*)d_in[10];
    float* out = (float*)d_out;

    const float scale = 0.07216878364870323f; // 1/sqrt(128+64)

    // ---- workspace (bytes), total 90.7 MB ----
    char* base = (char*)d_ws;
    ushort_t* WB1     = (ushort_t*)(base + 0);         // [1152][2048]       4.72 MB
    ushort_t* WukT_b  = (ushort_t*)(base + 4718592);   // [16][512][128]     2.10
    ushort_t* WuvT_b  = (ushort_t*)(base + 6815744);   // [512][2048]        2.10
    ushort_t* WB2     = (ushort_t*)(base + 8912896);   // [3072][512]        3.15
    ushort_t* veffT_b = (ushort_t*)(base + 12058624);  // [16][128][512]     2.10
    ushort_t* Wo_b    = (ushort_t*)(base + 14155776);  // [2048][2048]       8.39
    ushort_t* xb      = (ushort_t*)(base + 22544384);  // [4096][2048]       16.78
    ushort_t* XP      = (ushort_t*)(base + 39321600);  // [4096][1152]       9.44
    ushort_t* VT_all  = (ushort_t*)(base + 48758784);  // [2][16][128][2048] 16.78
    ushort_t* QP      = (ushort_t*)(base + 65536000);  // [4096][3072]       25.17

    // ---- prep ----
    cvt_f32_bf16<<<8192, 256, 0, stream>>>(x, xb, 2097152);
    cvt_f32_bf16<<<4096, 256, 0, stream>>>(W_o, Wo_b, 1048576);
    build_wb1<<<2304, 256, 0, stream>>>(W_dq, W_dkv, W_kr, WB1);
    transpose_f32_bf16<<<dim3(16, 4, 16), 256, 0, stream>>>(W_uk, WukT_b, 128, 512, 65536, 65536);
    transpose_f32_bf16<<<dim3(16, 64, 1), 256, 0, stream>>>(W_uv, WuvT_b, 2048, 512, 0, 0);
    transpose_f32_bf16<<<dim3(64, 16, 1), 256, 0, stream>>>(W_uq, WB2, 512, 2048, 0, 0);
    cvt_f32_bf16<<<512, 256, 0, stream>>>(W_qr, WB2 + (ll)2048 * 512, 131072);

    // veffT[h][d][k] = sum_c Wo[h*128+d][c] * WuvT[k][c]
    gemmb(stream, Wo_b, WuvT_b, veffT_b, 128, 512, 2048, 2048, 2048, 512,
          16, 16, 0, 262144, 0, 0, 0, 65536, 0);

    // XP = xb . WB1^T  ->  [cq | c_kv | c_kr | pad]
    gemmb(stream, xb, WB1, XP, 4096, 1152, 2048, 2048, 2048, 1152,
          1, 1, 0, 0, 0, 0, 0, 0, 0);
    rope_kr<<<512, 256, 0, stream>>>(XP, cosb, sinb);

    // VT[b][h][d][s] = sum_k veffT[h][d][k] * c_kv[b][s][k]
    gemmb(stream, veffT_b, XP + 512, VT_all, 128, 2048, 512, 512, 1152, 2048,
          32, 16, 0, 65536, (ll)2048 * 1152, 0, (ll)16 * 262144, 262144, 0);

    // QP = cq . WB2^T  ->  [q_up | q_r]; rope q_r in place
    gemmb(stream, XP, WB2, QP, 4096, 3072, 512, 1152, 512, 3072,
          1, 1, 0, 0, 0, 0, 0, 0, 0);
    rope_qr_ip<<<8192, 256, 0, stream>>>(QP, cosb, sinb);

    // ---- fused attention ----
    flash_mla<<<dim3(32, 16, 2), 128, 0, stream>>>(QP, WukT_b, XP, VT_all, out, scale);

    (void)in_sizes; (void)n_in; (void)out_size; (void)ws_size;
}

// Round 7
// 587.641 us; speedup vs baseline: 1.8757x; 1.8757x over previous
//
#include <hip/hip_runtime.h>
#include <hip/hip_bf16.h>
#include <math.h>

typedef long long ll;
typedef unsigned short ushort_t;
typedef __attribute__((ext_vector_type(8))) __bf16 bf16x8;
typedef __attribute__((ext_vector_type(4))) float f32x4;

// ---------------- helpers ----------------
__device__ __forceinline__ ushort_t f2bf(float f) {
    __hip_bfloat16 h = __float2bfloat16(f);
    return *reinterpret_cast<ushort_t*>(&h);
}
__device__ __forceinline__ float bf2f(ushort_t u) {
    return __uint_as_float(((unsigned)u) << 16);
}
// global->LDS DMA: lds dest wave-uniform; lane i deposits at dest + i*16
__device__ __forceinline__ void stage16(const void* g_lane, void* lds_uniform) {
    __builtin_amdgcn_global_load_lds(
        (const __attribute__((address_space(1))) unsigned int*)g_lane,
        (__attribute__((address_space(3))) unsigned int*)lds_uniform, 16, 0, 0);
}

// ---------------- bf16 MFMA GEMM (B^T form), TK=64, double-buffered ----------------
//   C[z][m,n] = sum_k A[z][m,k] * B[z][n,k];  z1 = z/Z2, z2 = z%Z2
#define TM 128
#define TN 128
#define TK 64

__global__ __launch_bounds__(256)
void gemm_bf16(const ushort_t* __restrict__ Ab, const ushort_t* __restrict__ Bb,
               void* __restrict__ Cb,
               int M, int N, int K,
               int a_rs, int b_rs, int c_rs, int Z2,
               ll a_bs1, ll a_bs2, ll b_bs1, ll b_bs2, ll c_bs1, ll c_bs2,
               int out_f32)
{
    const int m0 = blockIdx.y * TM;
    const int n0 = blockIdx.x * TN;
    const int z1 = blockIdx.z / Z2, z2 = blockIdx.z % Z2;

    const ushort_t* A = Ab + z1 * a_bs1 + z2 * a_bs2;
    const ushort_t* B = Bb + z1 * b_bs1 + z2 * b_bs2;

    __shared__ ushort_t As[2][TM][TK];
    __shared__ ushort_t Bs[2][TN][TK];

    const int tid  = threadIdx.x;
    const int w    = tid >> 6;
    const int l    = tid & 63;
    const int lo16 = l & 15;
    const int quad = l >> 4;
    const int wm0  = (w & 1) * 64;
    const int wn0  = (w >> 1) * 64;

    const int srow  = l >> 3;
    const int sunit = (l & 7) ^ srow;

    f32x4 acc[4][4];
    const f32x4 zero = {0.f, 0.f, 0.f, 0.f};
#pragma unroll
    for (int mi = 0; mi < 4; ++mi)
#pragma unroll
        for (int nj = 0; nj < 4; ++nj) acc[mi][nj] = zero;

    const int nIter = K / TK;

#pragma unroll
    for (int i = 0; i < 4; ++i) {
        const int rr = w * 32 + i * 8;
        stage16(A + (ll)(m0 + rr + srow) * a_rs + sunit * 8, &As[0][rr][0]);
        stage16(B + (ll)(n0 + rr + srow) * b_rs + sunit * 8, &Bs[0][rr][0]);
    }

    int buf = 0;
    for (int it = 0; it < nIter; ++it) {
        __syncthreads();
        if (it + 1 < nIter) {
            const int k0 = (it + 1) * TK;
            const int nb = buf ^ 1;
#pragma unroll
            for (int i = 0; i < 4; ++i) {
                const int rr = w * 32 + i * 8;
                stage16(A + (ll)(m0 + rr + srow) * a_rs + (k0 + sunit * 8), &As[nb][rr][0]);
                stage16(B + (ll)(n0 + rr + srow) * b_rs + (k0 + sunit * 8), &Bs[nb][rr][0]);
            }
        }
#pragma unroll
        for (int h = 0; h < 2; ++h) {
            const int phys = (h * 4 + quad) ^ (lo16 & 7);
            bf16x8 af[4], bfr[4];
#pragma unroll
            for (int mi = 0; mi < 4; ++mi)
                af[mi] = *(const bf16x8*)&As[buf][wm0 + mi * 16 + lo16][phys * 8];
#pragma unroll
            for (int nj = 0; nj < 4; ++nj)
                bfr[nj] = *(const bf16x8*)&Bs[buf][wn0 + nj * 16 + lo16][phys * 8];
#pragma unroll
            for (int mi = 0; mi < 4; ++mi)
#pragma unroll
                for (int nj = 0; nj < 4; ++nj)
                    acc[mi][nj] = __builtin_amdgcn_mfma_f32_16x16x32_bf16(
                        af[mi], bfr[nj], acc[mi][nj], 0, 0, 0);
        }
        buf ^= 1;
    }

    if (out_f32) {
        float* C = (float*)Cb + z1 * c_bs1 + z2 * c_bs2;
#pragma unroll
        for (int mi = 0; mi < 4; ++mi)
#pragma unroll
            for (int r = 0; r < 4; ++r) {
                const ll row = m0 + wm0 + mi * 16 + quad * 4 + r;
                float* cr = C + row * (ll)c_rs + (n0 + wn0 + lo16);
#pragma unroll
                for (int nj = 0; nj < 4; ++nj) cr[nj * 16] = acc[mi][nj][r];
            }
    } else {
        ushort_t* C = (ushort_t*)Cb + z1 * c_bs1 + z2 * c_bs2;
#pragma unroll
        for (int mi = 0; mi < 4; ++mi)
#pragma unroll
            for (int r = 0; r < 4; ++r) {
                const ll row = m0 + wm0 + mi * 16 + quad * 4 + r;
                ushort_t* cr = C + row * (ll)c_rs + (n0 + wn0 + lo16);
#pragma unroll
                for (int nj = 0; nj < 4; ++nj) cr[nj * 16] = f2bf(acc[mi][nj][r]);
            }
    }
}

// ---------------- fused flash-MLA attention (4-wave, round-4 structure) ----------------
// Grid (32,16,2), 256 thr. LDS 48KB -> 3 blocks/CU co-resident.
#define QP_RS 3072
#define XP_RS 1152

__global__ __launch_bounds__(256, 2)
void flash_mla(const ushort_t* __restrict__ QP,    // [2][2048][3072]: q_up | q_r
               const ushort_t* __restrict__ WukT,  // [16][512][128]
               const ushort_t* __restrict__ XP,    // [2][2048][1152]: cq | K(576) | pad
               const ushort_t* __restrict__ VT,    // [2][16][128][2048]
               float* __restrict__ out,            // [2][2048][2048]
               float scale)
{
    const int qt = 31 - blockIdx.x;
    const int h  = blockIdx.y;
    const int b  = blockIdx.z;
    const int t0 = qt * 64;

    // build: Aq[64][16u]@0 (16384) | Bw[64][16u]@16384 (16384) | Q3[4][16][72]@32768 (9216)
    // main : Ks[32][72u]@0 (36864) | Vs[128][4u]@36864 (8192) | P[4][1024B]@45056 (4096)
    __shared__ __align__(16) char smem[49152];
    ushort_t* Ks = (ushort_t*)smem;
    ushort_t* Vs = (ushort_t*)(smem + 36864);
    ushort_t* Q3 = (ushort_t*)(smem + 32768);
    ushort_t* Aq = (ushort_t*)smem;
    ushort_t* Bw = (ushort_t*)(smem + 16384);

    const int tid  = threadIdx.x;
    const int w    = tid >> 6;
    const int l    = tid & 63;
    const int lo16 = l & 15;
    const int quad = l >> 4;

    // ---- phase 1: build Q A-frags qa[0..17] (k-tiles of 32 over 576) ----
    bf16x8 qa[18];

#pragma unroll
    for (int i = 0; i < 4; ++i) {
        int p = w * 256 + i * 64 + l;
        int r = p >> 4, u = p & 15, ul = u ^ (r & 15);
        stage16(QP + (ll)(b * 2048 + t0 + r) * QP_RS + h * 128 + ul * 8,
                (char*)Aq + (ll)(w * 256 + i * 64) * 16);
    }
#pragma unroll
    for (int i = 0; i < 4; ++i) {
        int p = w * 256 + i * 64 + l;
        int r = p >> 4, u = p & 15, ul = u ^ (r & 15);
        stage16(WukT + ((ll)h * 512 + r) * 128 + ul * 8,
                (char*)Bw + (ll)(w * 256 + i * 64) * 16);
    }
    __syncthreads();

    bf16x8 ab[4];
#pragma unroll
    for (int kd = 0; kd < 4; ++kd)
        ab[kd] = *(const bf16x8*)(Aq + (16 * w + lo16) * 128 + (((kd * 4 + quad) ^ lo16) & 15) * 8);

    for (int kc = 0; kc < 8; ++kc) {
#pragma unroll
        for (int nt = 0; nt < 4; ++nt) {
            f32x4 c = {0.f, 0.f, 0.f, 0.f};
#pragma unroll
            for (int kd = 0; kd < 4; ++kd) {
                bf16x8 bb = *(const bf16x8*)(Bw + (nt * 16 + lo16) * 128 +
                                             (((kd * 4 + quad) ^ lo16) & 15) * 8);
                c = __builtin_amdgcn_mfma_f32_16x16x32_bf16(ab[kd], bb, c, 0, 0, 0);
            }
#pragma unroll
            for (int r = 0; r < 4; ++r)
                Q3[(w * 16 + quad * 4 + r) * 72 + nt * 16 + lo16] = f2bf(c[r]);
        }
#pragma unroll
        for (int kd2 = 0; kd2 < 2; ++kd2)
            qa[kc * 2 + kd2] = *(const bf16x8*)(Q3 + (w * 16 + lo16) * 72 + kd2 * 32 + quad * 8);

        if (kc < 7) {
            __syncthreads();
#pragma unroll
            for (int i = 0; i < 4; ++i) {
                int p = w * 256 + i * 64 + l;
                int r = p >> 4, u = p & 15, ul = u ^ (r & 15);
                stage16(WukT + ((ll)h * 512 + (kc + 1) * 64 + r) * 128 + ul * 8,
                        (char*)Bw + (ll)(w * 256 + i * 64) * 16);
            }
            __syncthreads();
        }
    }
    // rope tail (k-tiles 16,17) from QP cols 2048..3071
#pragma unroll
    for (int kt = 16; kt < 18; ++kt)
        qa[kt] = *(const bf16x8*)(QP + (ll)(b * 2048 + t0 + 16 * w + lo16) * QP_RS +
                                  2048 + h * 64 + (kt - 16) * 32 + quad * 8);

    // ---- phase 2: K/V loop ----
    f32x4 oacc[8];
    const f32x4 zero = {0.f, 0.f, 0.f, 0.f};
#pragma unroll
    for (int dt = 0; dt < 8; ++dt) oacc[dt] = zero;
    float mrow[4], lrow[4];
#pragma unroll
    for (int r = 0; r < 4; ++r) { mrow[r] = -3.0e38f; lrow[r] = 0.f; }

    char* Pw = smem + 45056 + w * 1024;
    const int nst = 2 * qt + 2;
    for (int st = 0; st < nst; ++st) {
        const int s0 = st * 32;
        __syncthreads();
        // stage Ks[32 rows][72 units]: wave w covers rows 8w..8w+8
#pragma unroll
        for (int i = 0; i < 9; ++i) {
            int p = i * 64 + l;                 // 0..575
            int r = 8 * w + p / 72, u = p % 72, ul = u ^ (r & 7);
            stage16(XP + (ll)(b * 2048 + s0 + r) * XP_RS + 512 + ul * 8,
                    (char*)Ks + (ll)(w * 576 + i * 64) * 16);
        }
        // stage Vs[128 rows][4 units]
#pragma unroll
        for (int i = 0; i < 2; ++i) {
            int p = w * 128 + i * 64 + l;
            int r = p >> 2, u = p & 3, ul = u ^ (r & 3);
            stage16(VT + ((ll)(b * 16 + h) * 128 + r) * 2048 + s0 + ul * 8,
                    (char*)Vs + (ll)(w * 128 + i * 64) * 16);
        }
        __syncthreads();

        // S = Q.K^T (fp32), 16x32 per wave
        f32x4 sc[2];
        sc[0] = zero; sc[1] = zero;
#pragma unroll
        for (int kt = 0; kt < 18; ++kt)
#pragma unroll
            for (int nt = 0; nt < 2; ++nt) {
                int phys = (kt * 4 + quad) ^ (lo16 & 7);
                bf16x8 kb = *(const bf16x8*)(Ks + (nt * 16 + lo16) * 576 + phys * 8);
                sc[nt] = __builtin_amdgcn_mfma_f32_16x16x32_bf16(qa[kt], kb, sc[nt], 0, 0, 0);
            }

        // scale + causal mask (diagonal tiles st >= 2*qt)
        const int rbase = 16 * w + quad * 4;    // row - t0
#pragma unroll
        for (int nt = 0; nt < 2; ++nt)
#pragma unroll
            for (int r = 0; r < 4; ++r) sc[nt][r] *= scale;
        if (st >= 2 * qt) {
#pragma unroll
            for (int nt = 0; nt < 2; ++nt)
#pragma unroll
                for (int r = 0; r < 4; ++r)
                    if ((s0 + nt * 16 + lo16) > (t0 + rbase + r))
                        sc[nt][r] = -INFINITY;
        }

        // online softmax per row
        float alpha[4];
#pragma unroll
        for (int r = 0; r < 4; ++r) {
            float tm = fmaxf(sc[0][r], sc[1][r]);
#pragma unroll
            for (int off = 1; off <= 8; off <<= 1)
                tm = fmaxf(tm, __shfl_xor(tm, off, 64));
            float mnew = fmaxf(mrow[r], tm);
            alpha[r] = __expf(mrow[r] - mnew);
            mrow[r] = mnew;
            sc[0][r] = __expf(sc[0][r] - mnew);
            sc[1][r] = __expf(sc[1][r] - mnew);
            float rs = sc[0][r] + sc[1][r];
#pragma unroll
            for (int off = 1; off <= 8; off <<= 1)
                rs += __shfl_xor(rs, off, 64);
            lrow[r] = lrow[r] * alpha[r] + rs;
        }
#pragma unroll
        for (int dt = 0; dt < 8; ++dt)
#pragma unroll
            for (int r = 0; r < 4; ++r) oacc[dt][r] *= alpha[r];

        // P -> bf16 -> wave-private swizzled LDS (1KB/wave) -> A-frag
#pragma unroll
        for (int nt = 0; nt < 2; ++nt)
#pragma unroll
            for (int r = 0; r < 4; ++r) {
                int row = quad * 4 + r;
                int col = nt * 16 + lo16;
                *(ushort_t*)(Pw + row * 64 + (((col >> 3) ^ (row & 3)) << 4) + (col & 7) * 2)
                    = f2bf(sc[nt][r]);
            }
        bf16x8 pf = *(const bf16x8*)(Pw + lo16 * 64 + (quad ^ (lo16 & 3)) * 16);

        // O += P.V
#pragma unroll
        for (int dt = 0; dt < 8; ++dt) {
            int phys = quad ^ (lo16 & 3);
            bf16x8 vb = *(const bf16x8*)(Vs + (dt * 16 + lo16) * 32 + phys * 8);
            oacc[dt] = __builtin_amdgcn_mfma_f32_16x16x32_bf16(pf, vb, oacc[dt], 0, 0, 0);
        }
    }

    // ---- epilogue ----
#pragma unroll
    for (int r = 0; r < 4; ++r) {
        const float inv = 1.0f / lrow[r];
        const ll row = (ll)(b * 2048 + t0 + 16 * w + quad * 4 + r);
#pragma unroll
        for (int dt = 0; dt < 8; ++dt)
            out[row * 2048 + h * 128 + dt * 16 + lo16] = oacc[dt][r] * inv;
    }
}

// ---------------- conversion / layout kernels ----------------
__global__ void cvt_f32_bf16(const float* __restrict__ in, ushort_t* __restrict__ out, ll n4)
{
    ll i = (ll)blockIdx.x * 256 + threadIdx.x;
    if (i >= n4) return;
    float4 v = *(const float4*)(in + i * 4);
    ushort4 u;
    u.x = f2bf(v.x); u.y = f2bf(v.y); u.z = f2bf(v.z); u.w = f2bf(v.w);
    *(ushort4*)(out + i * 4) = u;
}

// WB1 [1152][2048]: 0..511 W_dq | 512..1023 W_dkv | 1024..1087 W_kr | pad 0
__global__ void build_wb1(const float* __restrict__ Wdq, const float* __restrict__ Wdkv,
                          const float* __restrict__ Wkr, ushort_t* __restrict__ out)
{
    ll i4 = ((ll)blockIdx.x * 256 + threadIdx.x) * 4;
    if (i4 >= (ll)1152 * 2048) return;
    int row = (int)(i4 >> 11);
    int col = (int)(i4 & 2047);
    float4 v = make_float4(0.f, 0.f, 0.f, 0.f);
    if (row < 512)       v = *(const float4*)(Wdq + (ll)row * 2048 + col);
    else if (row < 1024) v = *(const float4*)(Wdkv + (ll)(row - 512) * 2048 + col);
    else if (row < 1088) v = *(const float4*)(Wkr + (ll)(row - 1024) * 2048 + col);
    ushort4 u;
    u.x = f2bf(v.x); u.y = f2bf(v.y); u.z = f2bf(v.z); u.w = f2bf(v.w);
    *(ushort4*)(out + i4) = u;
}

__global__ void transpose_f32_bf16(const float* __restrict__ in, ushort_t* __restrict__ out,
                                   int R, int C, ll in_bs, ll out_bs)
{
    __shared__ float tile[32][33];
    const float* I = in + (ll)blockIdx.z * in_bs;
    ushort_t*    O = out + (ll)blockIdx.z * out_bs;
    int r0 = blockIdx.y * 32, c0 = blockIdx.x * 32;
    int tx = threadIdx.x & 31, ty = threadIdx.x >> 5;
#pragma unroll
    for (int i = 0; i < 4; ++i)
        tile[ty + i * 8][tx] = I[(ll)(r0 + ty + i * 8) * C + (c0 + tx)];
    __syncthreads();
#pragma unroll
    for (int i = 0; i < 4; ++i)
        O[(ll)(c0 + ty + i * 8) * R + (r0 + tx)] = f2bf(tile[tx][ty + i * 8]);
}

// rope on XP cols [1024..1088) in place (bf16)
__global__ void rope_kr(ushort_t* __restrict__ XP, const float* __restrict__ cb,
                        const float* __restrict__ sb)
{
    int idx = blockIdx.x * 256 + threadIdx.x;   // 2*2048*32
    if (idx >= 2 * 2048 * 32) return;
    int j = idx & 31, t = (idx >> 5) & 2047, b = idx >> 16;
    float c = cb[t * 32 + j], s = sb[t * 32 + j];
    ushort_t* p = XP + ((ll)(b * 2048 + t)) * 1152 + 1024 + 2 * j;
    float re = bf2f(p[0]), im = bf2f(p[1]);
    p[0] = f2bf(re * c - im * s);
    p[1] = f2bf(re * s + im * c);
}

// rope on QP cols [2048..3072) in place (bf16)
__global__ void rope_qr_ip(ushort_t* __restrict__ QP, const float* __restrict__ cb,
                           const float* __restrict__ sb)
{
    int idx = blockIdx.x * 256 + threadIdx.x;   // 4096*512 pairs
    if (idx >= 4096 * 512) return;
    int pj = idx & 511, h = pj >> 5, j = pj & 31;
    int row = idx >> 9;
    int t = row & 2047;
    float c = cb[t * 32 + j], s = sb[t * 32 + j];
    ll base = (ll)row * 3072 + 2048 + h * 64 + 2 * j;
    float re = bf2f(QP[base]), im = bf2f(QP[base + 1]);
    QP[base]     = f2bf(re * c - im * s);
    QP[base + 1] = f2bf(re * s + im * c);
}

// ---------------- host ----------------
static inline void gemmb(hipStream_t st, const ushort_t* A, const ushort_t* B, void* C,
                         int M, int N, int K, int a_rs, int b_rs, int c_rs,
                         int nb, int Z2,
                         ll a_bs1, ll a_bs2, ll b_bs1, ll b_bs2, ll c_bs1, ll c_bs2,
                         int of32)
{
    dim3 g(N / TN, M / TM, nb);
    gemm_bf16<<<g, 256, 0, st>>>(A, B, C, M, N, K, a_rs, b_rs, c_rs, Z2,
                                 a_bs1, a_bs2, b_bs1, b_bs2, c_bs1, c_bs2, of32);
}

extern "C" void kernel_launch(void* const* d_in, const int* in_sizes, int n_in,
                              void* d_out, int out_size, void* d_ws, size_t ws_size,
                              hipStream_t stream)
{
    const float* x     = (const float*)d_in[0];
    const float* cosb  = (const float*)d_in[1];
    const float* sinb  = (const float*)d_in[2];
    const float* W_dq  = (const float*)d_in[3];
    const float* W_uq  = (const float*)d_in[4];
    const float* W_dkv = (const float*)d_in[5];
    const float* W_uk  = (const float*)d_in[6];
    const float* W_uv  = (const float*)d_in[7];
    const float* W_qr  = (const float*)d_in[8];
    const float* W_kr  = (const float*)d_in[9];
    const float* W_o   = (const float*)d_in[10];
    float* out = (float*)d_out;

    const float scale = 0.07216878364870323f; // 1/sqrt(128+64)

    // ---- workspace (bytes), total 90.7 MB ----
    char* base = (char*)d_ws;
    ushort_t* WB1     = (ushort_t*)(base + 0);         // [1152][2048]       4.72 MB
    ushort_t* WukT_b  = (ushort_t*)(base + 4718592);   // [16][512][128]     2.10
    ushort_t* WuvT_b  = (ushort_t*)(base + 6815744);   // [512][2048]        2.10
    ushort_t* WB2     = (ushort_t*)(base + 8912896);   // [3072][512]        3.15
    ushort_t* veffT_b = (ushort_t*)(base + 12058624);  // [16][128][512]     2.10
    ushort_t* Wo_b    = (ushort_t*)(base + 14155776);  // [2048][2048]       8.39
    ushort_t* xb      = (ushort_t*)(base + 22544384);  // [4096][2048]       16.78
    ushort_t* XP      = (ushort_t*)(base + 39321600);  // [4096][1152]       9.44
    ushort_t* VT_all  = (ushort_t*)(base + 48758784);  // [2][16][128][2048] 16.78
    ushort_t* QP      = (ushort_t*)(base + 65536000);  // [4096][3072]       25.17

    // ---- prep ----
    cvt_f32_bf16<<<8192, 256, 0, stream>>>(x, xb, 2097152);
    cvt_f32_bf16<<<4096, 256, 0, stream>>>(W_o, Wo_b, 1048576);
    build_wb1<<<2304, 256, 0, stream>>>(W_dq, W_dkv, W_kr, WB1);
    transpose_f32_bf16<<<dim3(16, 4, 16), 256, 0, stream>>>(W_uk, WukT_b, 128, 512, 65536, 65536);
    transpose_f32_bf16<<<dim3(16, 64, 1), 256, 0, stream>>>(W_uv, WuvT_b, 2048, 512, 0, 0);
    transpose_f32_bf16<<<dim3(64, 16, 1), 256, 0, stream>>>(W_uq, WB2, 512, 2048, 0, 0);
    cvt_f32_bf16<<<512, 256, 0, stream>>>(W_qr, WB2 + (ll)2048 * 512, 131072);

    // veffT[h][d][k] = sum_c Wo[h*128+d][c] * WuvT[k][c]
    gemmb(stream, Wo_b, WuvT_b, veffT_b, 128, 512, 2048, 2048, 2048, 512,
          16, 16, 0, 262144, 0, 0, 0, 65536, 0);

    // XP = xb . WB1^T  ->  [cq | c_kv | c_kr | pad]
    gemmb(stream, xb, WB1, XP, 4096, 1152, 2048, 2048, 2048, 1152,
          1, 1, 0, 0, 0, 0, 0, 0, 0);
    rope_kr<<<512, 256, 0, stream>>>(XP, cosb, sinb);

    // VT[b][h][d][s] = sum_k veffT[h][d][k] * c_kv[b][s][k]
    gemmb(stream, veffT_b, XP + 512, VT_all, 128, 2048, 512, 512, 1152, 2048,
          32, 16, 0, 65536, (ll)2048 * 1152, 0, (ll)16 * 262144, 262144, 0);

    // QP = cq . WB2^T  ->  [q_up | q_r]; rope q_r in place
    gemmb(stream, XP, WB2, QP, 4096, 3072, 512, 1152, 512, 3072,
          1, 1, 0, 0, 0, 0, 0, 0, 0);
    rope_qr_ip<<<8192, 256, 0, stream>>>(QP, cosb, sinb);

    // ---- fused attention ----
    flash_mla<<<dim3(32, 16, 2), 256, 0, stream>>>(QP, WukT_b, XP, VT_all, out, scale);

    (void)in_sizes; (void)n_in; (void)out_size; (void)ws_size;
}